// Round 8
// baseline (159.700 us; speedup 1.0000x reference)
//
#include <hip/hip_runtime.h>

typedef __attribute__((ext_vector_type(8))) short bf16x8;
typedef __attribute__((ext_vector_type(4))) float f32x4;
typedef __attribute__((ext_vector_type(4))) unsigned short us4;

__device__ __forceinline__ unsigned short f2bf(float f) {
    unsigned int u = __builtin_bit_cast(unsigned int, f);
    unsigned int r = (u + 0x7fffu + ((u >> 16) & 1u)) >> 16;
    return (unsigned short)r;
}

// Grid barrier for 256 co-resident blocks (grid=256, 1/CU, launch_bounds(256,1)).
// System-scope release/acquire so per-XCD L2s write back / invalidate.
__device__ __forceinline__ void gbar(unsigned int* ctr) {
    __syncthreads();                                   // drains vmcnt for all waves
    if (threadIdx.x == 0) {
        __builtin_amdgcn_fence(__ATOMIC_SEQ_CST, "");  // system release: L2 writeback
        __hip_atomic_fetch_add(ctr, 1u, __ATOMIC_RELEASE, __HIP_MEMORY_SCOPE_SYSTEM);
        while (__hip_atomic_load(ctr, __ATOMIC_ACQUIRE,
                                 __HIP_MEMORY_SCOPE_SYSTEM) < 256u)
            __builtin_amdgcn_s_sleep(2);
    }
    __syncthreads();
    __builtin_amdgcn_fence(__ATOMIC_ACQUIRE, "");      // system acquire: invalidate
}

// ---------------------------------------------------------------------------
// Fused independent prep (validated R3 kernel, unchanged).
__global__ __launch_bounds__(256) void k_aux(
    const float* __restrict__ idx_emb, const float* __restrict__ msg_W1,
    float* __restrict__ rc,
    const float* __restrict__ t_grad, float* __restrict__ tg,
    const float* __restrict__ y, unsigned short* __restrict__ xbf,
    const float* __restrict__ gnn_W, unsigned short* __restrict__ WbfT) {
    __shared__ float red[4][64];
    int bx = blockIdx.x, t = threadIdx.x;
    if (bx < 128) {
        int tid = bx * 256 + t;
        int h = tid & 7, n = (tid >> 3) & 1023, t_ = (tid >> 13) & 1, k = tid >> 14;
        const float* wv = msg_W1 + k * 1032 + h * 129 + 1 + t_ * 64;
        const float* e = idx_emb + n * 64;
        float s = 0.f;
#pragma unroll
        for (int d = 0; d < 64; ++d) s += e[d] * wv[d];
        rc[(k * 2 + t_) * 8192 + n * 8 + h] = s;
    } else if (bx < 144) {
        int jl = t & 63, sg = t >> 6;
        int j = (bx - 128) * 64 + jl;
        float acc = 0.f;
        for (int i = 0; i < 256; ++i) acc += t_grad[(sg * 256 + i) * 1024 + j];
        red[sg][jl] = acc;
        __syncthreads();
        if (sg == 0)
            tg[j] = (red[0][jl] + red[1][jl] + red[2][jl] + red[3][jl]) * (1.f / 1024.f);
    } else if (bx < 160) {
        int base = (bx - 144) * 4096 + t;
#pragma unroll
        for (int p = 0; p < 16; ++p) xbf[base + p * 256] = f2bf(y[base + p * 256]);
    } else if (bx < 175) {
        int wi = bx - 160;                      // l*5 + j
        const float* src = gnn_W + wi * 4096;
        unsigned short* dst = WbfT + wi * 4096; // [c][d] = W[d][c]
        int c = t & 63, dg = t >> 6;
#pragma unroll
        for (int p = 0; p < 16; ++p) {
            int d = dg + p * 4;
            dst[c * 64 + d] = f2bf(src[d * 64 + c]);
        }
    }
}

// ---------------------------------------------------------------------------
// Fused msg-MLP + bf16 convert + transpose (validated R3 kernel, unchanged).
__global__ __launch_bounds__(256) void k_msgcvt(
    const float* __restrict__ adj, const float* __restrict__ adj_deriv,
    const float* __restrict__ W1, const float* __restrict__ b1,
    const float* __restrict__ W2, const float* __restrict__ b2,
    const float* __restrict__ W3, const float* __restrict__ b3,
    const float* __restrict__ rc, unsigned short* __restrict__ Abf) {
    int mt = blockIdx.x, nt = blockIdx.y, z = blockIdx.z;
    const float* A = z ? adj_deriv : adj;
    unsigned short* D0 = Abf + z * 2097152;
    unsigned short* D1 = D0 + 1048576;
    int k = z;

    float wa[8], b1v[8], w2[64], b2v[8], w3v[8];
#pragma unroll
    for (int h = 0; h < 8; ++h) {
        wa[h]  = W1[k * 1032 + h * 129];
        b1v[h] = b1[k * 8 + h];
        b2v[h] = b2[k * 8 + h];
        w3v[h] = W3[k * 8 + h];
    }
#pragma unroll
    for (int i = 0; i < 64; ++i) w2[i] = W2[k * 64 + i];
    float b3v = b3[k];

    int t = threadIdx.x;
    int c = t & 63, rg = t >> 6;
    const float* colp = rc + (k * 2 + 1) * 8192 + (mt * 64 + c) * 8;
    float cm[8];
    *(float4*)&cm[0] = *(const float4*)colp;
    *(float4*)&cm[4] = *(const float4*)(colp + 4);
    const float* rowp = rc + (k * 2) * 8192 + (nt * 64) * 8;

    __shared__ unsigned short tile[64][65];
#pragma unroll
    for (int p = 0; p < 16; ++p) {
        int r = rg + 4 * p;                     // wave-uniform row
        float av = A[(nt * 64 + r) * 1024 + mt * 64 + c];
        float rn[8];
        *(float4*)&rn[0] = *(const float4*)(rowp + r * 8);
        *(float4*)&rn[4] = *(const float4*)(rowp + r * 8 + 4);
        float h1[8];
#pragma unroll
        for (int h = 0; h < 8; ++h) {
            float v = av * wa[h] + rn[h] + cm[h] + b1v[h];
            h1[h] = v > 0.f ? v : 0.f;
        }
        float o = b3v;
#pragma unroll
        for (int kk = 0; kk < 8; ++kk) {
            float s = b2v[kk];
#pragma unroll
            for (int h = 0; h < 8; ++h) s += h1[h] * w2[kk * 8 + h];
            s = s > 0.f ? s : 0.f;
            o += s * w3v[kk];
        }
        unsigned short us = f2bf(o);
        D0[(nt * 64 + r) * 1024 + mt * 64 + c] = us;
        tile[r][c] = us;
    }
    __syncthreads();
#pragma unroll
    for (int p = 0; p < 16; ++p) {
        int r = rg + 4 * p;
        D1[(mt * 64 + r) * 1024 + nt * 64 + c] = tile[c][r];
    }
}

// ---------------------------------------------------------------------------
// One GNN layer: gemm phase (R3 k_gemm2 verbatim; x from GLOBAL xin) -> gbar
// -> post phase (R3 k_post verbatim). grid (16 nt, 16 ms) = 256 blocks.
// L<2: xout = relu(sum P + u4 + b) as bf16. L==2: out = tg * (...).
template<int L>
__global__ __launch_bounds__(256, 1) void k_layerfull(
    const unsigned short* __restrict__ Abf,
    const unsigned short* __restrict__ xin,
    const unsigned short* __restrict__ WT,    // this layer: [5][64 c][64 d]
    const float* __restrict__ bvec,           // gnn_b + L*64
    const float* __restrict__ tg,
    float* __restrict__ u4, float* __restrict__ P,
    unsigned short* __restrict__ xout, float* __restrict__ out,
    unsigned int* __restrict__ bar) {
    int nt = blockIdx.x, ms = blockIdx.y;
    int t = threadIdx.x, w = t >> 6, l64 = t & 63;
    int lr = l64 & 15, lk = l64 >> 4, klo = 8 * lk;
    int m0 = ms * 64;
    __shared__ unsigned short uTs[16384];    // [4 j][64 c][64 m] bf16, swizzled

    // ---- u-phase: u[m][c] = sum_d x[m][d] W[d][c] via MFMA ----
    int mrow = m0 + w * 16 + lr;
    bf16x8 xa0 = *(const bf16x8*)&xin[mrow * 64 + klo];
    bf16x8 xa1 = *(const bf16x8*)&xin[mrow * 64 + 32 + klo];
    int njmax = (nt == 0) ? 5 : 4;
    for (int j = 0; j < njmax; ++j) {
        f32x4 au[4];
#pragma unroll
        for (int cf = 0; cf < 4; ++cf) au[cf] = (f32x4){0.f, 0.f, 0.f, 0.f};
#pragma unroll
        for (int cf = 0; cf < 4; ++cf) {
            bf16x8 wf0 = *(const bf16x8*)&WT[(j * 64 + cf * 16 + lr) * 64 + klo];
            bf16x8 wf1 = *(const bf16x8*)&WT[(j * 64 + cf * 16 + lr) * 64 + 32 + klo];
            au[cf] = __builtin_amdgcn_mfma_f32_16x16x32_bf16(xa0, wf0, au[cf], 0, 0, 0);
            au[cf] = __builtin_amdgcn_mfma_f32_16x16x32_bf16(xa1, wf1, au[cf], 0, 0, 0);
        }
        if (j < 4) {
#pragma unroll
            for (int cf = 0; cf < 4; ++cf) {
                int cc = cf * 16 + lr;
                us4 pk;
                pk[0] = f2bf(au[cf][0]); pk[1] = f2bf(au[cf][1]);
                pk[2] = f2bf(au[cf][2]); pk[3] = f2bf(au[cf][3]);
                int off = ((j * 64 + cc) * 64 + w * 16 + lk * 4) * 2;
                *(us4*)((char*)uTs + (off ^ ((cc & 7) << 4))) = pk;
            }
        } else {
#pragma unroll
            for (int cf = 0; cf < 4; ++cf)
#pragma unroll
                for (int r = 0; r < 4; ++r)
                    u4[(m0 + w * 16 + lk * 4 + r) * 64 + cf * 16 + lr] = au[cf][r];
        }
    }
    __syncthreads();

    // ---- main: P = a@u0 + aT@u1 + ad@u2 + adT@u3 over this m-window ----
    f32x4 acc[4];
#pragma unroll
    for (int cf = 0; cf < 4; ++cf) acc[cf] = (f32x4){0.f, 0.f, 0.f, 0.f};
    int arow = nt * 64 + w * 16 + lr;
#pragma unroll
    for (int j = 0; j < 4; ++j) {
#pragma unroll
        for (int kk = 0; kk < 2; ++kk) {
            bf16x8 af = *(const bf16x8*)&Abf[j * 1048576 + arow * 1024 + m0 + kk * 32 + klo];
#pragma unroll
            for (int cf = 0; cf < 4; ++cf) {
                int cc = cf * 16 + lr;
                int off = ((j * 64 + cc) * 64 + kk * 32 + klo) * 2;
                bf16x8 bfr = *(const bf16x8*)((char*)uTs + (off ^ ((cc & 7) << 4)));
                acc[cf] = __builtin_amdgcn_mfma_f32_16x16x32_bf16(af, bfr, acc[cf], 0, 0, 0);
            }
        }
    }
    float* Pp = P + ms * 65536;
    int nbase = nt * 64 + w * 16 + lk * 4;
#pragma unroll
    for (int cf = 0; cf < 4; ++cf)
#pragma unroll
        for (int r = 0; r < 4; ++r)
            Pp[(nbase + r) * 64 + cf * 16 + lr] = acc[cf][r];

    // ---- grid barrier (all 256 blocks co-resident) ----
    gbar(bar);

    // ---- post phase (R3 k_post verbatim) ----
    {
        int bid = blockIdx.y * 16 + blockIdx.x;
        int idx = bid * 256 + t;
        int n = idx >> 6, c = idx & 63;
        float s = u4[idx] + bvec[c];
#pragma unroll
        for (int k2 = 0; k2 < 16; ++k2) s += P[k2 * 65536 + idx];
        if (L < 2) {
            s = fmaxf(s, 0.f);
            xout[idx] = f2bf(s);
        } else {
            out[idx] = tg[n] * s;
        }
    }
}

// ---------------------------------------------------------------------------
extern "C" void kernel_launch(void* const* d_in, const int* in_sizes, int n_in,
                              void* d_out, int out_size, void* d_ws, size_t ws_size,
                              hipStream_t stream) {
    const float* y         = (const float*)d_in[0];
    const float* adj       = (const float*)d_in[1];
    const float* adj_deriv = (const float*)d_in[2];
    const float* t_grad    = (const float*)d_in[3];
    const float* idx_emb   = (const float*)d_in[4];
    const float* msg_W1    = (const float*)d_in[5];
    const float* msg_b1    = (const float*)d_in[6];
    const float* msg_W2    = (const float*)d_in[7];
    const float* msg_b2    = (const float*)d_in[8];
    const float* msg_W3    = (const float*)d_in[9];
    const float* msg_b3    = (const float*)d_in[10];
    const float* gnn_W     = (const float*)d_in[11];
    const float* gnn_b     = (const float*)d_in[12];
    float* outp = (float*)d_out;

    float* ws = (float*)d_ws;
    unsigned int* bar = (unsigned int*)ws;                   // 16 uints (64 B)
    float* rc   = ws + 64;                                   // 32768 f
    float* tg   = ws + 32832;                                // 1024 f
    float* u4   = ws + 33856;                                // 65536 f
    float* P    = ws + 99392;                                // 1048576 f
    unsigned short* xbfA = (unsigned short*)(ws + 1147968);  // 65536 us
    unsigned short* xbfB = (unsigned short*)(ws + 1180736);  // 65536 us
    unsigned short* WbfT = (unsigned short*)(ws + 1213504);  // 61440 us
    unsigned short* Abf  = (unsigned short*)(ws + 1244224);  // 4194304 us
    // end: 3341376 floats = 13.4 MB

    hipMemsetAsync(bar, 0, 64, stream);   // zero barrier counters every call
    k_aux<<<175, 256, 0, stream>>>(idx_emb, msg_W1, rc, t_grad, tg,
                                   y, xbfA, gnn_W, WbfT);
    k_msgcvt<<<dim3(16, 16, 2), 256, 0, stream>>>(adj, adj_deriv,
                                                  msg_W1, msg_b1, msg_W2, msg_b2,
                                                  msg_W3, msg_b3, rc, Abf);
    k_layerfull<0><<<dim3(16, 16), 256, 0, stream>>>(Abf, xbfA, WbfT,
                                                     gnn_b, tg, u4, P,
                                                     xbfB, outp, &bar[0]);
    k_layerfull<1><<<dim3(16, 16), 256, 0, stream>>>(Abf, xbfB, WbfT + 20480,
                                                     gnn_b + 64, tg, u4, P,
                                                     xbfA, outp, &bar[1]);
    k_layerfull<2><<<dim3(16, 16), 256, 0, stream>>>(Abf, xbfA, WbfT + 40960,
                                                     gnn_b + 128, tg, u4, P,
                                                     xbfB, outp, &bar[2]);
}

// Round 9
// 113.769 us; speedup vs baseline: 1.4037x; 1.4037x over previous
//
#include <hip/hip_runtime.h>

typedef __attribute__((ext_vector_type(8))) short bf16x8;
typedef __attribute__((ext_vector_type(4))) float f32x4;
typedef __attribute__((ext_vector_type(4))) unsigned short us4;

__device__ __forceinline__ unsigned short f2bf(float f) {
    unsigned int u = __builtin_bit_cast(unsigned int, f);
    unsigned int r = (u + 0x7fffu + ((u >> 16) & 1u)) >> 16;
    return (unsigned short)r;
}

// ---------------------------------------------------------------------------
// Fused independent prep (validated R3 kernel, unchanged).
__global__ __launch_bounds__(256) void k_aux(
    const float* __restrict__ idx_emb, const float* __restrict__ msg_W1,
    float* __restrict__ rc,
    const float* __restrict__ t_grad, float* __restrict__ tg,
    const float* __restrict__ y, unsigned short* __restrict__ xbf,
    const float* __restrict__ gnn_W, unsigned short* __restrict__ WbfT) {
    __shared__ float red[4][64];
    int bx = blockIdx.x, t = threadIdx.x;
    if (bx < 128) {
        int tid = bx * 256 + t;
        int h = tid & 7, n = (tid >> 3) & 1023, t_ = (tid >> 13) & 1, k = tid >> 14;
        const float* wv = msg_W1 + k * 1032 + h * 129 + 1 + t_ * 64;
        const float* e = idx_emb + n * 64;
        float s = 0.f;
#pragma unroll
        for (int d = 0; d < 64; ++d) s += e[d] * wv[d];
        rc[(k * 2 + t_) * 8192 + n * 8 + h] = s;
    } else if (bx < 144) {
        int jl = t & 63, sg = t >> 6;
        int j = (bx - 128) * 64 + jl;
        float acc = 0.f;
        for (int i = 0; i < 256; ++i) acc += t_grad[(sg * 256 + i) * 1024 + j];
        red[sg][jl] = acc;
        __syncthreads();
        if (sg == 0)
            tg[j] = (red[0][jl] + red[1][jl] + red[2][jl] + red[3][jl]) * (1.f / 1024.f);
    } else if (bx < 160) {
        int base = (bx - 144) * 4096 + t;
#pragma unroll
        for (int p = 0; p < 16; ++p) xbf[base + p * 256] = f2bf(y[base + p * 256]);
    } else if (bx < 175) {
        int wi = bx - 160;                      // l*5 + j
        const float* src = gnn_W + wi * 4096;
        unsigned short* dst = WbfT + wi * 4096; // [c][d] = W[d][c]
        int c = t & 63, dg = t >> 6;
#pragma unroll
        for (int p = 0; p < 16; ++p) {
            int d = dg + p * 4;
            dst[c * 64 + d] = f2bf(src[d * 64 + c]);
        }
    }
}

// ---------------------------------------------------------------------------
// Union: bx<512 = msg-MLP tile (validated R3 k_msgcvt body, flattened grid);
// bx>=512 = uT0 compute (validated gemm2 u-phase): uT0[j][c][m] for 64-row
// stripe, from xbf @ WT(layer0), j=0..3, written transposed bf16.
__global__ __launch_bounds__(256) void k_msgu(
    const float* __restrict__ adj, const float* __restrict__ adj_deriv,
    const float* __restrict__ W1, const float* __restrict__ b1,
    const float* __restrict__ W2, const float* __restrict__ b2,
    const float* __restrict__ W3, const float* __restrict__ b3,
    const float* __restrict__ rc, unsigned short* __restrict__ Abf,
    const unsigned short* __restrict__ xbf,
    const unsigned short* __restrict__ WbfT,
    unsigned short* __restrict__ uT0) {
    int bx = blockIdx.x, t = threadIdx.x;
    if (bx < 512) {
        int mt = bx & 15, nt = (bx >> 4) & 15, z = bx >> 8;
        const float* A = z ? adj_deriv : adj;
        unsigned short* D0 = Abf + z * 2097152;
        unsigned short* D1 = D0 + 1048576;
        int k = z;

        float wa[8], b1v[8], w2[64], b2v[8], w3v[8];
#pragma unroll
        for (int h = 0; h < 8; ++h) {
            wa[h]  = W1[k * 1032 + h * 129];
            b1v[h] = b1[k * 8 + h];
            b2v[h] = b2[k * 8 + h];
            w3v[h] = W3[k * 8 + h];
        }
#pragma unroll
        for (int i = 0; i < 64; ++i) w2[i] = W2[k * 64 + i];
        float b3v = b3[k];

        int c = t & 63, rg = t >> 6;
        const float* colp = rc + (k * 2 + 1) * 8192 + (mt * 64 + c) * 8;
        float cm[8];
        *(float4*)&cm[0] = *(const float4*)colp;
        *(float4*)&cm[4] = *(const float4*)(colp + 4);
        const float* rowp = rc + (k * 2) * 8192 + (nt * 64) * 8;

        __shared__ unsigned short tile[64][65];
#pragma unroll
        for (int p = 0; p < 16; ++p) {
            int r = rg + 4 * p;                     // wave-uniform row
            float av = A[(nt * 64 + r) * 1024 + mt * 64 + c];
            float rn[8];
            *(float4*)&rn[0] = *(const float4*)(rowp + r * 8);
            *(float4*)&rn[4] = *(const float4*)(rowp + r * 8 + 4);
            float h1[8];
#pragma unroll
            for (int h = 0; h < 8; ++h) {
                float v = av * wa[h] + rn[h] + cm[h] + b1v[h];
                h1[h] = v > 0.f ? v : 0.f;
            }
            float o = b3v;
#pragma unroll
            for (int kk = 0; kk < 8; ++kk) {
                float s = b2v[kk];
#pragma unroll
                for (int h = 0; h < 8; ++h) s += h1[h] * w2[kk * 8 + h];
                s = s > 0.f ? s : 0.f;
                o += s * w3v[kk];
            }
            unsigned short us = f2bf(o);
            D0[(nt * 64 + r) * 1024 + mt * 64 + c] = us;
            tile[r][c] = us;
        }
        __syncthreads();
#pragma unroll
        for (int p = 0; p < 16; ++p) {
            int r = rg + 4 * p;
            D1[(mt * 64 + r) * 1024 + nt * 64 + c] = tile[c][r];
        }
    } else {
        // uT0 blocks: 16 blocks x 64 rows (validated u-phase, WT from global)
        int sb = bx - 512;
        int w = t >> 6, l = t & 63, lr = l & 15, lk = l >> 4, klo = 8 * lk;
        int m0 = sb * 64;
        int mrow = m0 + w * 16 + lr;
        bf16x8 xa0 = *(const bf16x8*)&xbf[mrow * 64 + klo];
        bf16x8 xa1 = *(const bf16x8*)&xbf[mrow * 64 + 32 + klo];
#pragma unroll
        for (int j = 0; j < 4; ++j) {
            f32x4 au[4];
#pragma unroll
            for (int cf = 0; cf < 4; ++cf) au[cf] = (f32x4){0.f, 0.f, 0.f, 0.f};
#pragma unroll
            for (int cf = 0; cf < 4; ++cf) {
                bf16x8 wf0 = *(const bf16x8*)&WbfT[(j * 64 + cf * 16 + lr) * 64 + klo];
                bf16x8 wf1 = *(const bf16x8*)&WbfT[(j * 64 + cf * 16 + lr) * 64 + 32 + klo];
                au[cf] = __builtin_amdgcn_mfma_f32_16x16x32_bf16(xa0, wf0, au[cf], 0, 0, 0);
                au[cf] = __builtin_amdgcn_mfma_f32_16x16x32_bf16(xa1, wf1, au[cf], 0, 0, 0);
            }
#pragma unroll
            for (int cf = 0; cf < 4; ++cf) {
                int cc = cf * 16 + lr;
                us4 pk;
                pk[0] = f2bf(au[cf][0]); pk[1] = f2bf(au[cf][1]);
                pk[2] = f2bf(au[cf][2]); pk[3] = f2bf(au[cf][3]);
                *(us4*)&uT0[(j * 64 + cc) * 1024 + m0 + w * 16 + lk * 4] = pk;
            }
        }
    }
}

// ---------------------------------------------------------------------------
// Stripe layer: 128 blocks x 8 owned rows, FULL K=1024 (no split-K partials).
// Wave w covers k in [w*256,(w+1)*256); u4-term folded into wave 0; LDS
// reduce of 4 wave-partials; fused post; next-layer uT rows via u-phase MFMA.
template<int L>
__global__ __launch_bounds__(256) void k_stripe(
    const unsigned short* __restrict__ Abf,
    const unsigned short* __restrict__ uTin,
    const unsigned short* __restrict__ xin,
    const unsigned short* __restrict__ WbfT,
    const float* __restrict__ gnn_b, const float* __restrict__ tg,
    unsigned short* __restrict__ xout, unsigned short* __restrict__ uTout,
    float* __restrict__ out) {
    __shared__ float pLDS[4][16][64];
    __shared__ unsigned short xns[8 * 72];       // padded stride 72
    int t = threadIdx.x, w = t >> 6, l = t & 63;
    int lr = l & 15, lk = l >> 4, klo = 8 * lk;
    int r0 = blockIdx.x * 8;

    f32x4 acc[4];
#pragma unroll
    for (int cf = 0; cf < 4; ++cf) acc[cf] = (f32x4){0.f, 0.f, 0.f, 0.f};

    int arow = min(r0 + lr, 1023);               // rows 8-15 redundant/discarded
#pragma unroll
    for (int j = 0; j < 4; ++j) {
        const unsigned short* Aj = Abf + j * 1048576 + arow * 1024;
        const unsigned short* Uj = uTin + j * 65536;
#pragma unroll
        for (int ks = 0; ks < 8; ++ks) {
            int kb = w * 256 + ks * 32;
            bf16x8 af = *(const bf16x8*)&Aj[kb + klo];
#pragma unroll
            for (int cf = 0; cf < 4; ++cf) {
                bf16x8 bfr = *(const bf16x8*)&Uj[(cf * 16 + lr) * 1024 + kb + klo];
                acc[cf] = __builtin_amdgcn_mfma_f32_16x16x32_bf16(af, bfr, acc[cf], 0, 0, 0);
            }
        }
    }
    if (w == 0) {                                // u4 term: x @ W4 (K=64)
        const unsigned short* W4 = WbfT + L * 20480 + 16384;
        const unsigned short* xr = xin + arow * 64;
#pragma unroll
        for (int kk = 0; kk < 2; ++kk) {
            bf16x8 af = *(const bf16x8*)&xr[kk * 32 + klo];
#pragma unroll
            for (int cf = 0; cf < 4; ++cf) {
                bf16x8 bfr = *(const bf16x8*)&W4[(cf * 16 + lr) * 64 + kk * 32 + klo];
                acc[cf] = __builtin_amdgcn_mfma_f32_16x16x32_bf16(af, bfr, acc[cf], 0, 0, 0);
            }
        }
    }
#pragma unroll
    for (int cf = 0; cf < 4; ++cf)
#pragma unroll
        for (int r = 0; r < 4; ++r)
            pLDS[w][lk * 4 + r][cf * 16 + lr] = acc[cf][r];
    __syncthreads();

    // ---- fused post: 2 outputs/thread over the 8 owned rows ----
    const float* bv = gnn_b + L * 64;
#pragma unroll
    for (int p = 0; p < 2; ++p) {
        int idx = t + p * 256;
        int row = idx >> 6, col = idx & 63;
        float s = pLDS[0][row][col] + pLDS[1][row][col] +
                  pLDS[2][row][col] + pLDS[3][row][col] + bv[col];
        if constexpr (L < 2) {
            float v = fmaxf(s, 0.f);
            unsigned short h = f2bf(v);
            xout[(r0 + row) * 64 + col] = h;
            xns[row * 72 + col] = h;
        } else {
            out[(r0 + row) * 64 + col] = tg[r0 + row] * s;
        }
    }

    if constexpr (L < 2) {
        __syncthreads();
        // ---- next-layer uT rows via u-phase MFMA: wave w handles j = w ----
        const unsigned short* WTn = WbfT + (L + 1) * 20480;
        int j = w;
        f32x4 au[4];
#pragma unroll
        for (int cf = 0; cf < 4; ++cf) au[cf] = (f32x4){0.f, 0.f, 0.f, 0.f};
#pragma unroll
        for (int kk = 0; kk < 2; ++kk) {
            bf16x8 af = *(const bf16x8*)&xns[(lr & 7) * 72 + kk * 32 + klo];
#pragma unroll
            for (int cf = 0; cf < 4; ++cf) {
                bf16x8 bfr = *(const bf16x8*)&WTn[(j * 64 + cf * 16 + lr) * 64 + kk * 32 + klo];
                au[cf] = __builtin_amdgcn_mfma_f32_16x16x32_bf16(af, bfr, au[cf], 0, 0, 0);
            }
        }
        if (lk < 2) {                            // C rows 0-7 only (8-15 dup)
#pragma unroll
            for (int cf = 0; cf < 4; ++cf) {
                int cc = cf * 16 + lr;
                us4 pk;
                pk[0] = f2bf(au[cf][0]); pk[1] = f2bf(au[cf][1]);
                pk[2] = f2bf(au[cf][2]); pk[3] = f2bf(au[cf][3]);
                *(us4*)&uTout[(j * 64 + cc) * 1024 + r0 + lk * 4] = pk;
            }
        }
    }
}

// ---------------------------------------------------------------------------
extern "C" void kernel_launch(void* const* d_in, const int* in_sizes, int n_in,
                              void* d_out, int out_size, void* d_ws, size_t ws_size,
                              hipStream_t stream) {
    const float* y         = (const float*)d_in[0];
    const float* adj       = (const float*)d_in[1];
    const float* adj_deriv = (const float*)d_in[2];
    const float* t_grad    = (const float*)d_in[3];
    const float* idx_emb   = (const float*)d_in[4];
    const float* msg_W1    = (const float*)d_in[5];
    const float* msg_b1    = (const float*)d_in[6];
    const float* msg_W2    = (const float*)d_in[7];
    const float* msg_b2    = (const float*)d_in[8];
    const float* msg_W3    = (const float*)d_in[9];
    const float* msg_b3    = (const float*)d_in[10];
    const float* gnn_W     = (const float*)d_in[11];
    const float* gnn_b     = (const float*)d_in[12];
    float* outp = (float*)d_out;

    float* ws = (float*)d_ws;
    float* rc = ws;                                          // 32768 f
    float* tg = ws + 32768;                                  // 1024 f
    unsigned short* xbfA = (unsigned short*)(ws + 33792);    // 65536 us
    unsigned short* xbfB = (unsigned short*)(ws + 66560);    // 65536 us
    unsigned short* WbfT = (unsigned short*)(ws + 99328);    // 61440 us
    unsigned short* uTA  = (unsigned short*)(ws + 130048);   // 262144 us
    unsigned short* uTB  = (unsigned short*)(ws + 261120);   // 262144 us
    unsigned short* Abf  = (unsigned short*)(ws + 392192);   // 4194304 us
    // end: 2489344 floats = 10.0 MB

    k_aux<<<175, 256, 0, stream>>>(idx_emb, msg_W1, rc, t_grad, tg,
                                   y, xbfA, gnn_W, WbfT);
    k_msgu<<<528, 256, 0, stream>>>(adj, adj_deriv,
                                    msg_W1, msg_b1, msg_W2, msg_b2,
                                    msg_W3, msg_b3, rc, Abf,
                                    xbfA, WbfT, uTA);
    k_stripe<0><<<128, 256, 0, stream>>>(Abf, uTA, xbfA, WbfT, gnn_b, tg,
                                         xbfB, uTB, outp);
    k_stripe<1><<<128, 256, 0, stream>>>(Abf, uTB, xbfB, WbfT, gnn_b, tg,
                                         xbfA, uTA, outp);
    k_stripe<2><<<128, 256, 0, stream>>>(Abf, uTA, xbfA, WbfT, gnn_b, tg,
                                         xbfB, uTB, outp);
}

// Round 10
// 102.038 us; speedup vs baseline: 1.5651x; 1.1150x over previous
//
#include <hip/hip_runtime.h>

typedef __attribute__((ext_vector_type(8))) short bf16x8;
typedef __attribute__((ext_vector_type(4))) float f32x4;
typedef __attribute__((ext_vector_type(4))) unsigned short us4;

__device__ __forceinline__ unsigned short f2bf(float f) {
    unsigned int u = __builtin_bit_cast(unsigned int, f);
    unsigned int r = (u + 0x7fffu + ((u >> 16) & 1u)) >> 16;
    return (unsigned short)r;
}

// ---------------------------------------------------------------------------
// Fused independent prep (validated R3 kernel) + counter zeroing (bx==175).
__global__ __launch_bounds__(256) void k_aux(
    const float* __restrict__ idx_emb, const float* __restrict__ msg_W1,
    float* __restrict__ rc,
    const float* __restrict__ t_grad, float* __restrict__ tg,
    const float* __restrict__ y, unsigned short* __restrict__ xbf,
    const float* __restrict__ gnn_W, unsigned short* __restrict__ WbfT,
    unsigned int* __restrict__ cnt) {
    __shared__ float red[4][64];
    int bx = blockIdx.x, t = threadIdx.x;
    if (bx < 128) {
        int tid = bx * 256 + t;
        int h = tid & 7, n = (tid >> 3) & 1023, t_ = (tid >> 13) & 1, k = tid >> 14;
        const float* wv = msg_W1 + k * 1032 + h * 129 + 1 + t_ * 64;
        const float* e = idx_emb + n * 64;
        float s = 0.f;
#pragma unroll
        for (int d = 0; d < 64; ++d) s += e[d] * wv[d];
        rc[(k * 2 + t_) * 8192 + n * 8 + h] = s;
    } else if (bx < 144) {
        int jl = t & 63, sg = t >> 6;
        int j = (bx - 128) * 64 + jl;
        float acc = 0.f;
        for (int i = 0; i < 256; ++i) acc += t_grad[(sg * 256 + i) * 1024 + j];
        red[sg][jl] = acc;
        __syncthreads();
        if (sg == 0)
            tg[j] = (red[0][jl] + red[1][jl] + red[2][jl] + red[3][jl]) * (1.f / 1024.f);
    } else if (bx < 160) {
        int base = (bx - 144) * 4096 + t;
#pragma unroll
        for (int p = 0; p < 16; ++p) xbf[base + p * 256] = f2bf(y[base + p * 256]);
    } else if (bx < 175) {
        int wi = bx - 160;                      // l*5 + j
        const float* src = gnn_W + wi * 4096;
        unsigned short* dst = WbfT + wi * 4096; // [c][d] = W[d][c]
        int c = t & 63, dg = t >> 6;
#pragma unroll
        for (int p = 0; p < 16; ++p) {
            int d = dg + p * 4;
            dst[c * 64 + d] = f2bf(src[d * 64 + c]);
        }
    } else {
        if (t < 16)
            __hip_atomic_store(&cnt[t], 0u, __ATOMIC_RELAXED, __HIP_MEMORY_SCOPE_AGENT);
    }
}

// ---------------------------------------------------------------------------
// Fused msg-MLP + bf16 convert + transpose (validated R3 kernel, unchanged).
__global__ __launch_bounds__(256) void k_msgcvt(
    const float* __restrict__ adj, const float* __restrict__ adj_deriv,
    const float* __restrict__ W1, const float* __restrict__ b1,
    const float* __restrict__ W2, const float* __restrict__ b2,
    const float* __restrict__ W3, const float* __restrict__ b3,
    const float* __restrict__ rc, unsigned short* __restrict__ Abf) {
    int mt = blockIdx.x, nt = blockIdx.y, z = blockIdx.z;
    const float* A = z ? adj_deriv : adj;
    unsigned short* D0 = Abf + z * 2097152;
    unsigned short* D1 = D0 + 1048576;
    int k = z;

    float wa[8], b1v[8], w2[64], b2v[8], w3v[8];
#pragma unroll
    for (int h = 0; h < 8; ++h) {
        wa[h]  = W1[k * 1032 + h * 129];
        b1v[h] = b1[k * 8 + h];
        b2v[h] = b2[k * 8 + h];
        w3v[h] = W3[k * 8 + h];
    }
#pragma unroll
    for (int i = 0; i < 64; ++i) w2[i] = W2[k * 64 + i];
    float b3v = b3[k];

    int t = threadIdx.x;
    int c = t & 63, rg = t >> 6;
    const float* colp = rc + (k * 2 + 1) * 8192 + (mt * 64 + c) * 8;
    float cm[8];
    *(float4*)&cm[0] = *(const float4*)colp;
    *(float4*)&cm[4] = *(const float4*)(colp + 4);
    const float* rowp = rc + (k * 2) * 8192 + (nt * 64) * 8;

    __shared__ unsigned short tile[64][65];
#pragma unroll
    for (int p = 0; p < 16; ++p) {
        int r = rg + 4 * p;                     // wave-uniform row
        float av = A[(nt * 64 + r) * 1024 + mt * 64 + c];
        float rn[8];
        *(float4*)&rn[0] = *(const float4*)(rowp + r * 8);
        *(float4*)&rn[4] = *(const float4*)(rowp + r * 8 + 4);
        float h1[8];
#pragma unroll
        for (int h = 0; h < 8; ++h) {
            float v = av * wa[h] + rn[h] + cm[h] + b1v[h];
            h1[h] = v > 0.f ? v : 0.f;
        }
        float o = b3v;
#pragma unroll
        for (int kk = 0; kk < 8; ++kk) {
            float s = b2v[kk];
#pragma unroll
            for (int h = 0; h < 8; ++h) s += h1[h] * w2[kk * 8 + h];
            s = s > 0.f ? s : 0.f;
            o += s * w3v[kk];
        }
        unsigned short us = f2bf(o);
        D0[(nt * 64 + r) * 1024 + mt * 64 + c] = us;
        tile[r][c] = us;
    }
    __syncthreads();
#pragma unroll
    for (int p = 0; p < 16; ++p) {
        int r = rg + 4 * p;
        D1[(mt * 64 + r) * 1024 + nt * 64 + c] = tile[c][r];
    }
}

// ---------------------------------------------------------------------------
// Layer: R3 gemm2 body (u-phase j=0..3 -> swizzled LDS; 4-term main GEMM;
// u4 folded into ms==0 block's acc) + last-block-per-nt election epilogue
// (threadFenceReduction pattern; no spinning). grid (16 nt, 16 ms).
template<int L>
__global__ __launch_bounds__(256) void k_gf(
    const unsigned short* __restrict__ Abf,
    const unsigned short* __restrict__ xin,
    const unsigned short* __restrict__ WT,    // this layer: [5][64 c][64 d]
    const float* __restrict__ bvec,           // gnn_b + L*64
    const float* __restrict__ tg,
    float* __restrict__ P,
    unsigned int* __restrict__ cnt,           // 16 counters, self-resetting
    unsigned short* __restrict__ xout,
    float* __restrict__ out) {
    int nt = blockIdx.x, ms = blockIdx.y;
    int t = threadIdx.x, w = t >> 6, l64 = t & 63;
    int lr = l64 & 15, lk = l64 >> 4, klo = 8 * lk;
    int m0 = ms * 64;
    __shared__ unsigned short uTs[16384];    // [4 j][64 c][64 m] bf16, swizzled
    __shared__ int winflag;

    // ---- u-phase: u[m][c] = sum_d x[m][d] W[d][c], j=0..3 (validated) ----
    int mrow = m0 + w * 16 + lr;
    bf16x8 xa0 = *(const bf16x8*)&xin[mrow * 64 + klo];
    bf16x8 xa1 = *(const bf16x8*)&xin[mrow * 64 + 32 + klo];
#pragma unroll
    for (int j = 0; j < 4; ++j) {
        f32x4 au[4];
#pragma unroll
        for (int cf = 0; cf < 4; ++cf) au[cf] = (f32x4){0.f, 0.f, 0.f, 0.f};
#pragma unroll
        for (int cf = 0; cf < 4; ++cf) {
            bf16x8 wf0 = *(const bf16x8*)&WT[(j * 64 + cf * 16 + lr) * 64 + klo];
            bf16x8 wf1 = *(const bf16x8*)&WT[(j * 64 + cf * 16 + lr) * 64 + 32 + klo];
            au[cf] = __builtin_amdgcn_mfma_f32_16x16x32_bf16(xa0, wf0, au[cf], 0, 0, 0);
            au[cf] = __builtin_amdgcn_mfma_f32_16x16x32_bf16(xa1, wf1, au[cf], 0, 0, 0);
        }
#pragma unroll
        for (int cf = 0; cf < 4; ++cf) {
            int cc = cf * 16 + lr;
            us4 pk;
            pk[0] = f2bf(au[cf][0]); pk[1] = f2bf(au[cf][1]);
            pk[2] = f2bf(au[cf][2]); pk[3] = f2bf(au[cf][3]);
            int off = ((j * 64 + cc) * 64 + w * 16 + lk * 4) * 2;
            *(us4*)((char*)uTs + (off ^ ((cc & 7) << 4))) = pk;
        }
    }
    __syncthreads();

    // ---- main: P = a@u0 + aT@u1 + ad@u2 + adT@u3 over this m-window ----
    f32x4 acc[4];
#pragma unroll
    for (int cf = 0; cf < 4; ++cf) acc[cf] = (f32x4){0.f, 0.f, 0.f, 0.f};
    int arow = nt * 64 + w * 16 + lr;
#pragma unroll
    for (int j = 0; j < 4; ++j) {
#pragma unroll
        for (int kk = 0; kk < 2; ++kk) {
            bf16x8 af = *(const bf16x8*)&Abf[j * 1048576 + arow * 1024 + m0 + kk * 32 + klo];
#pragma unroll
            for (int cf = 0; cf < 4; ++cf) {
                int cc = cf * 16 + lr;
                int off = ((j * 64 + cc) * 64 + kk * 32 + klo) * 2;
                bf16x8 bfr = *(const bf16x8*)((char*)uTs + (off ^ ((cc & 7) << 4)));
                acc[cf] = __builtin_amdgcn_mfma_f32_16x16x32_bf16(af, bfr, acc[cf], 0, 0, 0);
            }
        }
    }
    if (ms == 0) {       // u4 term folded here: x[arow] @ W4 (K=64, validated R9)
        const unsigned short* W4 = WT + 16384;
        const unsigned short* xr = xin + arow * 64;
#pragma unroll
        for (int kk = 0; kk < 2; ++kk) {
            bf16x8 af = *(const bf16x8*)&xr[kk * 32 + klo];
#pragma unroll
            for (int cf = 0; cf < 4; ++cf) {
                bf16x8 bfr = *(const bf16x8*)&W4[(cf * 16 + lr) * 64 + kk * 32 + klo];
                acc[cf] = __builtin_amdgcn_mfma_f32_16x16x32_bf16(af, bfr, acc[cf], 0, 0, 0);
            }
        }
    }
    float* Pp = P + ms * 65536;
    int nbase = nt * 64 + w * 16 + lk * 4;
#pragma unroll
    for (int cf = 0; cf < 4; ++cf)
#pragma unroll
        for (int r = 0; r < 4; ++r)
            Pp[(nbase + r) * 64 + cf * 16 + lr] = acc[cf][r];

    // ---- election: 16th arriver for this nt performs the post ----
    __syncthreads();
    if (t == 0) {
        __threadfence();                       // publish P slice (agent scope)
        unsigned int old = __hip_atomic_fetch_add(&cnt[nt], 1u, __ATOMIC_ACQ_REL,
                                                  __HIP_MEMORY_SCOPE_AGENT);
        if (old == 15u) {
            __builtin_amdgcn_fence(__ATOMIC_ACQUIRE, "agent");  // inv caches
            __hip_atomic_store(&cnt[nt], 0u, __ATOMIC_RELAXED,
                               __HIP_MEMORY_SCOPE_AGENT);       // self-reset
            winflag = 1;
        } else winflag = 0;
    }
    __syncthreads();
    if (winflag) {
        // post for rows nt*64..nt*64+64 (4 MB/layer total; no amplification)
#pragma unroll
        for (int p = 0; p < 4; ++p) {
            int q = t + p * 256;               // float4 id over 64x16
            int row = q >> 4, c4 = (q & 15) * 4;
            int gi = (nt * 64 + row) * 64 + c4;
            float4 sv = *(const float4*)&bvec[c4];
#pragma unroll
            for (int k2 = 0; k2 < 16; ++k2) {
                float4 pv = *(const float4*)&P[k2 * 65536 + gi];
                sv.x += pv.x; sv.y += pv.y; sv.z += pv.z; sv.w += pv.w;
            }
            if constexpr (L < 2) {
                us4 pk;
                pk[0] = f2bf(fmaxf(sv.x, 0.f));
                pk[1] = f2bf(fmaxf(sv.y, 0.f));
                pk[2] = f2bf(fmaxf(sv.z, 0.f));
                pk[3] = f2bf(fmaxf(sv.w, 0.f));
                *(us4*)&xout[gi] = pk;
            } else {
                float tgv = tg[nt * 64 + row];
                *(float4*)&out[gi] = make_float4(tgv * sv.x, tgv * sv.y,
                                                 tgv * sv.z, tgv * sv.w);
            }
        }
    }
}

// ---------------------------------------------------------------------------
extern "C" void kernel_launch(void* const* d_in, const int* in_sizes, int n_in,
                              void* d_out, int out_size, void* d_ws, size_t ws_size,
                              hipStream_t stream) {
    const float* y         = (const float*)d_in[0];
    const float* adj       = (const float*)d_in[1];
    const float* adj_deriv = (const float*)d_in[2];
    const float* t_grad    = (const float*)d_in[3];
    const float* idx_emb   = (const float*)d_in[4];
    const float* msg_W1    = (const float*)d_in[5];
    const float* msg_b1    = (const float*)d_in[6];
    const float* msg_W2    = (const float*)d_in[7];
    const float* msg_b2    = (const float*)d_in[8];
    const float* msg_W3    = (const float*)d_in[9];
    const float* msg_b3    = (const float*)d_in[10];
    const float* gnn_W     = (const float*)d_in[11];
    const float* gnn_b     = (const float*)d_in[12];
    float* outp = (float*)d_out;

    float* ws = (float*)d_ws;
    unsigned int* cnt = (unsigned int*)ws;                   // 16 uints
    float* rc = ws + 64;                                     // 32768 f
    float* tg = ws + 32832;                                  // 1024 f
    float* P  = ws + 33856;                                  // 1048576 f
    unsigned short* xbfA = (unsigned short*)(ws + 1082432);  // 65536 us
    unsigned short* xbfB = (unsigned short*)(ws + 1115200);  // 65536 us
    unsigned short* WbfT = (unsigned short*)(ws + 1147968);  // 61440 us
    unsigned short* Abf  = (unsigned short*)(ws + 1178688);  // 4194304 us
    // end: ~3.28M floats = 13.1 MB

    k_aux<<<176, 256, 0, stream>>>(idx_emb, msg_W1, rc, t_grad, tg,
                                   y, xbfA, gnn_W, WbfT, cnt);
    k_msgcvt<<<dim3(16, 16, 2), 256, 0, stream>>>(adj, adj_deriv,
                                                  msg_W1, msg_b1, msg_W2, msg_b2,
                                                  msg_W3, msg_b3, rc, Abf);
    k_gf<0><<<dim3(16, 16), 256, 0, stream>>>(Abf, xbfA, WbfT, gnn_b, tg,
                                              P, cnt, xbfB, outp);
    k_gf<1><<<dim3(16, 16), 256, 0, stream>>>(Abf, xbfB, WbfT + 20480,
                                              gnn_b + 64, tg, P, cnt, xbfA, outp);
    k_gf<2><<<dim3(16, 16), 256, 0, stream>>>(Abf, xbfA, WbfT + 40960,
                                              gnn_b + 128, tg, P, cnt, xbfB, outp);
}

// Round 11
// 95.512 us; speedup vs baseline: 1.6720x; 1.0683x over previous
//
#include <hip/hip_runtime.h>

typedef __attribute__((ext_vector_type(8))) short bf16x8;
typedef __attribute__((ext_vector_type(4))) float f32x4;
typedef __attribute__((ext_vector_type(4))) unsigned short us4;

__device__ __forceinline__ unsigned short f2bf(float f) {
    unsigned int u = __builtin_bit_cast(unsigned int, f);
    unsigned int r = (u + 0x7fffu + ((u >> 16) & 1u)) >> 16;
    return (unsigned short)r;
}

// ---------------------------------------------------------------------------
// Fused independent prep (validated R3 kernel, unchanged).
__global__ __launch_bounds__(256) void k_aux(
    const float* __restrict__ idx_emb, const float* __restrict__ msg_W1,
    float* __restrict__ rc,
    const float* __restrict__ t_grad, float* __restrict__ tg,
    const float* __restrict__ y, unsigned short* __restrict__ xbf,
    const float* __restrict__ gnn_W, unsigned short* __restrict__ WbfT) {
    __shared__ float red[4][64];
    int bx = blockIdx.x, t = threadIdx.x;
    if (bx < 128) {
        int tid = bx * 256 + t;
        int h = tid & 7, n = (tid >> 3) & 1023, t_ = (tid >> 13) & 1, k = tid >> 14;
        const float* wv = msg_W1 + k * 1032 + h * 129 + 1 + t_ * 64;
        const float* e = idx_emb + n * 64;
        float s = 0.f;
#pragma unroll
        for (int d = 0; d < 64; ++d) s += e[d] * wv[d];
        rc[(k * 2 + t_) * 8192 + n * 8 + h] = s;
    } else if (bx < 144) {
        int jl = t & 63, sg = t >> 6;
        int j = (bx - 128) * 64 + jl;
        float acc = 0.f;
        for (int i = 0; i < 256; ++i) acc += t_grad[(sg * 256 + i) * 1024 + j];
        red[sg][jl] = acc;
        __syncthreads();
        if (sg == 0)
            tg[j] = (red[0][jl] + red[1][jl] + red[2][jl] + red[3][jl]) * (1.f / 1024.f);
    } else if (bx < 160) {
        int base = (bx - 144) * 4096 + t;
#pragma unroll
        for (int p = 0; p < 16; ++p) xbf[base + p * 256] = f2bf(y[base + p * 256]);
    } else if (bx < 175) {
        int wi = bx - 160;                      // l*5 + j
        const float* src = gnn_W + wi * 4096;
        unsigned short* dst = WbfT + wi * 4096; // [c][d] = W[d][c]
        int c = t & 63, dg = t >> 6;
#pragma unroll
        for (int p = 0; p < 16; ++p) {
            int d = dg + p * 4;
            dst[c * 64 + d] = f2bf(src[d * 64 + c]);
        }
    }
}

// ---------------------------------------------------------------------------
// Fused msg-MLP + bf16 convert + transpose (validated R3 kernel, unchanged).
__global__ __launch_bounds__(256) void k_msgcvt(
    const float* __restrict__ adj, const float* __restrict__ adj_deriv,
    const float* __restrict__ W1, const float* __restrict__ b1,
    const float* __restrict__ W2, const float* __restrict__ b2,
    const float* __restrict__ W3, const float* __restrict__ b3,
    const float* __restrict__ rc, unsigned short* __restrict__ Abf) {
    int mt = blockIdx.x, nt = blockIdx.y, z = blockIdx.z;
    const float* A = z ? adj_deriv : adj;
    unsigned short* D0 = Abf + z * 2097152;
    unsigned short* D1 = D0 + 1048576;
    int k = z;

    float wa[8], b1v[8], w2[64], b2v[8], w3v[8];
#pragma unroll
    for (int h = 0; h < 8; ++h) {
        wa[h]  = W1[k * 1032 + h * 129];
        b1v[h] = b1[k * 8 + h];
        b2v[h] = b2[k * 8 + h];
        w3v[h] = W3[k * 8 + h];
    }
#pragma unroll
    for (int i = 0; i < 64; ++i) w2[i] = W2[k * 64 + i];
    float b3v = b3[k];

    int t = threadIdx.x;
    int c = t & 63, rg = t >> 6;
    const float* colp = rc + (k * 2 + 1) * 8192 + (mt * 64 + c) * 8;
    float cm[8];
    *(float4*)&cm[0] = *(const float4*)colp;
    *(float4*)&cm[4] = *(const float4*)(colp + 4);
    const float* rowp = rc + (k * 2) * 8192 + (nt * 64) * 8;

    __shared__ unsigned short tile[64][65];
#pragma unroll
    for (int p = 0; p < 16; ++p) {
        int r = rg + 4 * p;                     // wave-uniform row
        float av = A[(nt * 64 + r) * 1024 + mt * 64 + c];
        float rn[8];
        *(float4*)&rn[0] = *(const float4*)(rowp + r * 8);
        *(float4*)&rn[4] = *(const float4*)(rowp + r * 8 + 4);
        float h1[8];
#pragma unroll
        for (int h = 0; h < 8; ++h) {
            float v = av * wa[h] + rn[h] + cm[h] + b1v[h];
            h1[h] = v > 0.f ? v : 0.f;
        }
        float o = b3v;
#pragma unroll
        for (int kk = 0; kk < 8; ++kk) {
            float s = b2v[kk];
#pragma unroll
            for (int h = 0; h < 8; ++h) s += h1[h] * w2[kk * 8 + h];
            s = s > 0.f ? s : 0.f;
            o += s * w3v[kk];
        }
        unsigned short us = f2bf(o);
        D0[(nt * 64 + r) * 1024 + mt * 64 + c] = us;
        tile[r][c] = us;
    }
    __syncthreads();
#pragma unroll
    for (int p = 0; p < 16; ++p) {
        int r = rg + 4 * p;
        D1[(mt * 64 + r) * 1024 + nt * 64 + c] = tile[c][r];
    }
}

// ---------------------------------------------------------------------------
// Layer kernel, S=4 split-K. grid (16 nt, 4 ms), 256 threads (4 waves).
// Prologue: build x-window (256 rows) in LDS — L==0: copy from xbf;
//           L>0: relu(sum_{s<4} Pin[s] + bprev) (R7-validated formula, S=4).
// Body: 4 chunks x { u-phase (R3) -> swizzled uTs ; main 4-term GEMM (R3) }.
// u4 folded into acc by the block whose m-window holds its rows (R10 fold).
template<int L>
__global__ __launch_bounds__(256) void k_g(
    const unsigned short* __restrict__ Abf,
    const unsigned short* __restrict__ xbf,   // L==0 input x
    const unsigned short* __restrict__ WT,    // this layer: [5][64 c][64 d]
    const float* __restrict__ bprev,          // gnn_b + (L-1)*64, L>0
    const float* __restrict__ Pin,            // previous layer slices, L>0
    float* __restrict__ Pout) {
    int nt = blockIdx.x, ms = blockIdx.y;
    int t = threadIdx.x, w = t >> 6, l64 = t & 63;
    int lr = l64 & 15, lk = l64 >> 4, klo = 8 * lk;
    __shared__ unsigned short xs[16384];     // [256 m][64 d] bf16 (32 KB)
    __shared__ unsigned short uTs[16384];    // [4 j][64 c][64 m] bf16, swizzled

    // ---- prologue: x-window rows [ms*256, ms*256+256) into xs ----
    if constexpr (L == 0) {
#pragma unroll
        for (int p = 0; p < 8; ++p) {
            int q = t + p * 256;             // us8 id in [0,2048)
            int e = q * 8;
            *(bf16x8*)&xs[e] = *(const bf16x8*)&xbf[ms * 16384 + e];
        }
    } else {
#pragma unroll
        for (int p = 0; p < 16; ++p) {
            int q = t + p * 256;             // float4 id in [0,4096)
            int row = q >> 4, c4 = (q & 15) * 4;
            int gi = (ms * 256 + row) * 64 + c4;
            float4 acc4 = *(const float4*)&bprev[c4];
#pragma unroll
            for (int s = 0; s < 4; ++s) {
                float4 pv = *(const float4*)&Pin[s * 65536 + gi];
                acc4.x += pv.x; acc4.y += pv.y; acc4.z += pv.z; acc4.w += pv.w;
            }
            us4 pk;
            pk[0] = f2bf(fmaxf(acc4.x, 0.f));
            pk[1] = f2bf(fmaxf(acc4.y, 0.f));
            pk[2] = f2bf(fmaxf(acc4.z, 0.f));
            pk[3] = f2bf(fmaxf(acc4.w, 0.f));
            *(us4*)&xs[row * 64 + c4] = pk;
        }
    }
    __syncthreads();

    f32x4 acc[4];
#pragma unroll
    for (int cf = 0; cf < 4; ++cf) acc[cf] = (f32x4){0.f, 0.f, 0.f, 0.f};

    // ---- u4 fold: block whose window holds its output rows (R10 pattern) ----
    if (ms == (nt >> 2)) {
        const unsigned short* W4 = WT + 16384;
        int xrow = (nt & 3) * 64 + w * 16 + lr;        // local to xs
#pragma unroll
        for (int kk = 0; kk < 2; ++kk) {
            bf16x8 af = *(const bf16x8*)&xs[xrow * 64 + kk * 32 + klo];
#pragma unroll
            for (int cf = 0; cf < 4; ++cf) {
                bf16x8 bfr = *(const bf16x8*)&W4[(cf * 16 + lr) * 64 + kk * 32 + klo];
                acc[cf] = __builtin_amdgcn_mfma_f32_16x16x32_bf16(af, bfr, acc[cf], 0, 0, 0);
            }
        }
    }

    // ---- 4 chunks of the validated R3 u-phase + main GEMM ----
    int arow = nt * 64 + w * 16 + lr;
    for (int ch = 0; ch < 4; ++ch) {
        if (ch > 0) __syncthreads();             // uTs reuse safety
        int mloc = ch * 64 + w * 16 + lr;
        bf16x8 xa0 = *(const bf16x8*)&xs[mloc * 64 + klo];
        bf16x8 xa1 = *(const bf16x8*)&xs[mloc * 64 + 32 + klo];
#pragma unroll
        for (int j = 0; j < 4; ++j) {
            f32x4 au[4];
#pragma unroll
            for (int cf = 0; cf < 4; ++cf) au[cf] = (f32x4){0.f, 0.f, 0.f, 0.f};
#pragma unroll
            for (int cf = 0; cf < 4; ++cf) {
                bf16x8 wf0 = *(const bf16x8*)&WT[(j * 64 + cf * 16 + lr) * 64 + klo];
                bf16x8 wf1 = *(const bf16x8*)&WT[(j * 64 + cf * 16 + lr) * 64 + 32 + klo];
                au[cf] = __builtin_amdgcn_mfma_f32_16x16x32_bf16(xa0, wf0, au[cf], 0, 0, 0);
                au[cf] = __builtin_amdgcn_mfma_f32_16x16x32_bf16(xa1, wf1, au[cf], 0, 0, 0);
            }
#pragma unroll
            for (int cf = 0; cf < 4; ++cf) {
                int cc = cf * 16 + lr;
                us4 pk;
                pk[0] = f2bf(au[cf][0]); pk[1] = f2bf(au[cf][1]);
                pk[2] = f2bf(au[cf][2]); pk[3] = f2bf(au[cf][3]);
                int off = ((j * 64 + cc) * 64 + w * 16 + lk * 4) * 2;
                *(us4*)((char*)uTs + (off ^ ((cc & 7) << 4))) = pk;
            }
        }
        __syncthreads();

        int m0 = ms * 256 + ch * 64;
#pragma unroll
        for (int j = 0; j < 4; ++j) {
#pragma unroll
            for (int kk = 0; kk < 2; ++kk) {
                bf16x8 af = *(const bf16x8*)&Abf[j * 1048576 + arow * 1024 + m0 + kk * 32 + klo];
#pragma unroll
                for (int cf = 0; cf < 4; ++cf) {
                    int cc = cf * 16 + lr;
                    int off = ((j * 64 + cc) * 64 + kk * 32 + klo) * 2;
                    bf16x8 bfr = *(const bf16x8*)((char*)uTs + (off ^ ((cc & 7) << 4)));
                    acc[cf] = __builtin_amdgcn_mfma_f32_16x16x32_bf16(af, bfr, acc[cf], 0, 0, 0);
                }
            }
        }
    }

    float* Pp = Pout + ms * 65536;
    int nbase = nt * 64 + w * 16 + lk * 4;
#pragma unroll
    for (int cf = 0; cf < 4; ++cf)
#pragma unroll
        for (int r = 0; r < 4; ++r)
            Pp[(nbase + r) * 64 + cf * 16 + lr] = acc[cf][r];
}

// ---------------------------------------------------------------------------
// Final: out = tg[n] * (sum_{s<4} P[s] + b)   (R3 k_post, S=4, mode 2)
__global__ void k_postf(const float* __restrict__ P, const float* __restrict__ b,
                        const float* __restrict__ tg, float* __restrict__ out) {
    int idx = blockIdx.x * 256 + threadIdx.x;
    int n = idx >> 6, c = idx & 63;
    float s = b[c];
#pragma unroll
    for (int k = 0; k < 4; ++k) s += P[k * 65536 + idx];
    out[idx] = tg[n] * s;
}

// ---------------------------------------------------------------------------
extern "C" void kernel_launch(void* const* d_in, const int* in_sizes, int n_in,
                              void* d_out, int out_size, void* d_ws, size_t ws_size,
                              hipStream_t stream) {
    const float* y         = (const float*)d_in[0];
    const float* adj       = (const float*)d_in[1];
    const float* adj_deriv = (const float*)d_in[2];
    const float* t_grad    = (const float*)d_in[3];
    const float* idx_emb   = (const float*)d_in[4];
    const float* msg_W1    = (const float*)d_in[5];
    const float* msg_b1    = (const float*)d_in[6];
    const float* msg_W2    = (const float*)d_in[7];
    const float* msg_b2    = (const float*)d_in[8];
    const float* msg_W3    = (const float*)d_in[9];
    const float* msg_b3    = (const float*)d_in[10];
    const float* gnn_W     = (const float*)d_in[11];
    const float* gnn_b     = (const float*)d_in[12];
    float* outp = (float*)d_out;

    float* ws = (float*)d_ws;
    float* rc = ws;                                          // 32768 f
    float* tg = ws + 32768;                                  // 1024 f
    float* PA = ws + 33792;                                  // 262144 f
    float* PB = ws + 295936;                                 // 262144 f
    unsigned short* xbfA = (unsigned short*)(ws + 558080);   // 65536 us
    unsigned short* WbfT = (unsigned short*)(ws + 590848);   // 61440 us
    unsigned short* Abf  = (unsigned short*)(ws + 621568);   // 4194304 us
    // end: 2718720 floats = 10.9 MB

    k_aux<<<175, 256, 0, stream>>>(idx_emb, msg_W1, rc, t_grad, tg,
                                   y, xbfA, gnn_W, WbfT);
    k_msgcvt<<<dim3(16, 16, 2), 256, 0, stream>>>(adj, adj_deriv,
                                                  msg_W1, msg_b1, msg_W2, msg_b2,
                                                  msg_W3, msg_b3, rc, Abf);
    k_g<0><<<dim3(16, 4), 256, 0, stream>>>(Abf, xbfA, WbfT,
                                            gnn_b, PA, PA);
    k_g<1><<<dim3(16, 4), 256, 0, stream>>>(Abf, xbfA, WbfT + 20480,
                                            gnn_b, PA, PB);
    k_g<2><<<dim3(16, 4), 256, 0, stream>>>(Abf, xbfA, WbfT + 40960,
                                            gnn_b + 64, PB, PA);
    k_postf<<<256, 256, 0, stream>>>(PA, gnn_b + 128, tg, outp);
}